// Round 3
// baseline (452.378 us; speedup 1.0000x reference)
//
#include <hip/hip_runtime.h>
#include <hip/hip_bf16.h>

#define NN 100000
#define NE 1600000
#define NG 128
#define FIN 128
#define HID 32
#define NCLS 10

#define ET (NE / 4)      // 400000 threads for 4-wide edge kernels

#define SCAN_B 1024
#define NB ((NN + SCAN_B - 1) / SCAN_B)   // 98

#define POOL_CHUNK 512
#define POOL_SEG 16
#define POOL_GSPAN 32
#define POOL_GRID ((NN + POOL_CHUNK - 1) / POOL_CHUNK)

// ---------------- init: zero accumulators ----------------
__global__ void k_init(int* __restrict__ counts, float* __restrict__ gsum,
                       float* __restrict__ gcnt) {
    int i = blockIdx.x * blockDim.x + threadIdx.x;
    int stride = gridDim.x * blockDim.x;
    for (int j = i; j < NN; j += stride) counts[j] = 0;
    for (int j = i; j < NG * HID; j += stride) gsum[j] = 0.f;
    for (int j = i; j < NG; j += stride) gcnt[j] = 0.f;
}

// ---------------- degree histogram over dst (4-wide, fire-and-forget atomics) ----
__global__ void k_hist(const int* __restrict__ dst, int* __restrict__ counts) {
    int tid = blockIdx.x * blockDim.x + threadIdx.x;
    if (tid >= ET) return;
    const int4 d = ((const int4*)dst)[tid];
    atomicAdd(&counts[d.x], 1);
    atomicAdd(&counts[d.y], 1);
    atomicAdd(&counts[d.z], 1);
    atomicAdd(&counts[d.w], 1);
}

// ---------------- scan phase A: per-block exclusive scan (+ dinv fused) --------
__global__ void k_scanA(const int* __restrict__ counts, int* __restrict__ row_ptr,
                        int* __restrict__ bsum, float* __restrict__ dinv) {
    __shared__ int lds[SCAN_B];
    int i = blockIdx.x * SCAN_B + threadIdx.x;
    int v = (i < NN) ? counts[i] : 0;
    if (i < NN) dinv[i] = rsqrtf((float)v + 1.0f);
    lds[threadIdx.x] = v;
    __syncthreads();
    int val = v;
    for (int off = 1; off < SCAN_B; off <<= 1) {
        int u = 0;
        if ((int)threadIdx.x >= off) u = lds[threadIdx.x - off];
        __syncthreads();
        if ((int)threadIdx.x >= off) { val += u; lds[threadIdx.x] = val; }
        __syncthreads();
    }
    if (i < NN) row_ptr[i] = val - v;            // exclusive within block
    if (threadIdx.x == SCAN_B - 1) bsum[blockIdx.x] = val;  // block total
}

// ---------------- scan phase B: scan block sums (single block) ----------------
__global__ void k_scanB(int* __restrict__ bsum) {
    __shared__ int lds[128];
    int t = threadIdx.x;
    int v = (t < NB) ? bsum[t] : 0;
    lds[t] = v;
    __syncthreads();
    int val = v;
    for (int off = 1; off < 128; off <<= 1) {
        int u = 0;
        if (t >= off) u = lds[t - off];
        __syncthreads();
        if (t >= off) { val += u; lds[t] = val; }
        __syncthreads();
    }
    if (t < NB) bsum[t] = val - v;               // exclusive
}

// ---------------- scan phase C: add offsets, init cursor ----------------
__global__ void k_scanC(int* __restrict__ row_ptr, int* __restrict__ cursor,
                        const int* __restrict__ bsum) {
    int i = blockIdx.x * SCAN_B + threadIdx.x;
    if (i < NN) {
        int r = row_ptr[i] + bsum[blockIdx.x];
        row_ptr[i] = r;
        cursor[i] = r;
    }
    if (i == 0) row_ptr[NN] = NE;
}

// ---------------- scatter edges into CSR slots (4-wide, 4 atomics in flight) ---
__global__ void k_scatter(const int* __restrict__ src, const int* __restrict__ dst,
                          int* __restrict__ cursor, int* __restrict__ csr_src) {
    int tid = blockIdx.x * blockDim.x + threadIdx.x;
    if (tid >= ET) return;
    const int4 d = ((const int4*)dst)[tid];
    const int4 s = ((const int4*)src)[tid];
    int p0 = atomicAdd(&cursor[d.x], 1);
    int p1 = atomicAdd(&cursor[d.y], 1);
    int p2 = atomicAdd(&cursor[d.z], 1);
    int p3 = atomicAdd(&cursor[d.w], 1);
    csr_src[p0] = s.x;
    csr_src[p1] = s.y;
    csr_src[p2] = s.z;
    csr_src[p3] = s.w;
}

// ---------------- layer-0 GEMM: t = (x @ W0) * dinv ----------------
__global__ void k_gemm0(const float* __restrict__ x, const float* __restrict__ W,
                        const float* __restrict__ dinv, float* __restrict__ t) {
    __shared__ float Ws[FIN * HID];
    for (int j = threadIdx.x; j < FIN * HID; j += 256) Ws[j] = W[j];
    __syncthreads();
    int gid = blockIdx.x * 256 + threadIdx.x;
    int i = gid >> 5, f = gid & 31;
    if (i >= NN) return;
    const float4* xr = (const float4*)(x + (size_t)i * FIN);
    float acc = 0.f;
#pragma unroll
    for (int k4 = 0; k4 < FIN / 4; k4++) {
        float4 xv = xr[k4];
        int kb = k4 * 4;
        acc = fmaf(xv.x, Ws[(kb + 0) * HID + f], acc);
        acc = fmaf(xv.y, Ws[(kb + 1) * HID + f], acc);
        acc = fmaf(xv.z, Ws[(kb + 2) * HID + f], acc);
        acc = fmaf(xv.w, Ws[(kb + 3) * HID + f], acc);
    }
    t[(size_t)i * HID + f] = acc * dinv[i];
}

// ---------------- hidden GEMM: t = (h @ W) * dinv ----------------
__global__ void k_gemmh(const float* __restrict__ h, const float* __restrict__ W,
                        const float* __restrict__ dinv, float* __restrict__ t) {
    __shared__ float Ws[HID * HID];
    for (int j = threadIdx.x; j < HID * HID; j += 256) Ws[j] = W[j];
    __syncthreads();
    int gid = blockIdx.x * 256 + threadIdx.x;
    int i = gid >> 5, f = gid & 31;
    if (i >= NN) return;
    const float4* hr = (const float4*)(h + (size_t)i * HID);
    float acc = 0.f;
#pragma unroll
    for (int k4 = 0; k4 < HID / 4; k4++) {
        float4 hv = hr[k4];
        int kb = k4 * 4;
        acc = fmaf(hv.x, Ws[(kb + 0) * HID + f], acc);
        acc = fmaf(hv.y, Ws[(kb + 1) * HID + f], acc);
        acc = fmaf(hv.z, Ws[(kb + 2) * HID + f], acc);
        acc = fmaf(hv.w, Ws[(kb + 3) * HID + f], acc);
    }
    t[(size_t)i * HID + f] = acc * dinv[i];
}

// ---------------- aggregation: lane = feature, 32 lanes/node, edge loop x4 -----
__global__ void k_agg(const float* __restrict__ t, const int* __restrict__ row_ptr,
                      const int* __restrict__ csr_src, const float* __restrict__ dinv,
                      const float* __restrict__ b, float* __restrict__ hout) {
    int gid = blockIdx.x * blockDim.x + threadIdx.x;
    int i = gid >> 5;                 // node
    int lane = threadIdx.x & 31;      // feature
    if (i >= NN) return;
    float acc = t[(size_t)i * HID + lane];          // self term t'[i]
    const int beg = row_ptr[i], end = row_ptr[i + 1];
    int e = beg;
    for (; e + 4 <= end; e += 4) {
        int s0 = csr_src[e + 0];
        int s1 = csr_src[e + 1];
        int s2 = csr_src[e + 2];
        int s3 = csr_src[e + 3];
        float v0 = t[(size_t)s0 * HID + lane];
        float v1 = t[(size_t)s1 * HID + lane];
        float v2 = t[(size_t)s2 * HID + lane];
        float v3 = t[(size_t)s3 * HID + lane];
        acc += (v0 + v1) + (v2 + v3);
    }
    for (; e < end; e++) {
        acc += t[(size_t)csr_src[e] * HID + lane];
    }
    float r = fmaf(acc, dinv[i], b[lane]);
    hout[(size_t)i * HID + lane] = fmaxf(r, 0.f);
}

// ---------------- pooling v2: register-segment accumulate -> LDS bins ----------
__global__ void k_pool2(const float* __restrict__ h, const int* __restrict__ batch,
                        float* __restrict__ gsum, float* __restrict__ gcnt) {
    __shared__ float lacc[POOL_GSPAN][HID];
    __shared__ float lcnt[POOL_GSPAN];
    __shared__ int s_gmin;
    const int chunk_start = blockIdx.x * POOL_CHUNK;

    for (int j = threadIdx.x; j < POOL_GSPAN * HID; j += 256) ((float*)lacc)[j] = 0.f;
    if (threadIdx.x < POOL_GSPAN) lcnt[threadIdx.x] = 0.f;
    if (threadIdx.x == 0) {
        int cs = chunk_start < NN ? chunk_start : NN - 1;
        s_gmin = batch[cs];
    }
    __syncthreads();
    const int gmin = s_gmin;

    const int seg = threadIdx.x >> 3;            // 0..31
    const int l = (threadIdx.x & 7) * 4;         // feature quad
    const int i0 = chunk_start + seg * POOL_SEG;

    float4 acc = {0.f, 0.f, 0.f, 0.f};
    float cnt = 0.f;
    int cur_g = -1;

    for (int k = 0; k < POOL_SEG; k++) {
        int i = i0 + k;
        if (i >= NN) break;
        int g = batch[i];
        if (g != cur_g) {
            if (cur_g >= 0) {
                int bin = cur_g - gmin;
                if (bin >= 0 && bin < POOL_GSPAN) {
                    atomicAdd(&lacc[bin][l + 0], acc.x);
                    atomicAdd(&lacc[bin][l + 1], acc.y);
                    atomicAdd(&lacc[bin][l + 2], acc.z);
                    atomicAdd(&lacc[bin][l + 3], acc.w);
                    if (l == 0) atomicAdd(&lcnt[bin], cnt);
                } else {
                    atomicAdd(&gsum[cur_g * HID + l + 0], acc.x);
                    atomicAdd(&gsum[cur_g * HID + l + 1], acc.y);
                    atomicAdd(&gsum[cur_g * HID + l + 2], acc.z);
                    atomicAdd(&gsum[cur_g * HID + l + 3], acc.w);
                    if (l == 0) atomicAdd(&gcnt[cur_g], cnt);
                }
            }
            cur_g = g;
            acc.x = acc.y = acc.z = acc.w = 0.f;
            cnt = 0.f;
        }
        const float4 v = *(const float4*)&h[(size_t)i * HID + l];
        acc.x += v.x; acc.y += v.y; acc.z += v.z; acc.w += v.w;
        cnt += 1.f;
    }
    if (cur_g >= 0) {
        int bin = cur_g - gmin;
        if (bin >= 0 && bin < POOL_GSPAN) {
            atomicAdd(&lacc[bin][l + 0], acc.x);
            atomicAdd(&lacc[bin][l + 1], acc.y);
            atomicAdd(&lacc[bin][l + 2], acc.z);
            atomicAdd(&lacc[bin][l + 3], acc.w);
            if (l == 0) atomicAdd(&lcnt[bin], cnt);
        } else {
            atomicAdd(&gsum[cur_g * HID + l + 0], acc.x);
            atomicAdd(&gsum[cur_g * HID + l + 1], acc.y);
            atomicAdd(&gsum[cur_g * HID + l + 2], acc.z);
            atomicAdd(&gsum[cur_g * HID + l + 3], acc.w);
            if (l == 0) atomicAdd(&gcnt[cur_g], cnt);
        }
    }
    __syncthreads();

    // drain LDS bins: one atomic per touched (graph, feature)
    for (int j = threadIdx.x; j < POOL_GSPAN * HID; j += 256) {
        int bin = j / HID, f = j % HID;
        int g = gmin + bin;
        float v = lacc[bin][f];
        if (g < NG && v != 0.f) atomicAdd(&gsum[g * HID + f], v);
    }
    if (threadIdx.x < POOL_GSPAN) {
        int g = gmin + threadIdx.x;
        float c = lcnt[threadIdx.x];
        if (g < NG && c != 0.f) atomicAdd(&gcnt[g], c);
    }
}

// ---------------- classifier + log_softmax ----------------
__global__ void k_classify(const float* __restrict__ gsum, const float* __restrict__ gcnt,
                           const float* __restrict__ Wl, const float* __restrict__ bl,
                           float* __restrict__ out) {
    __shared__ float w[HID * NCLS];
    __shared__ float bb[NCLS];
    int t = threadIdx.x;
    for (int j = t; j < HID * NCLS; j += blockDim.x) w[j] = Wl[j];
    if (t < NCLS) bb[t] = bl[t];
    __syncthreads();
    if (t >= NG) return;
    float c = gcnt[t];
    c = c > 1.f ? c : 1.f;
    float p[HID];
#pragma unroll
    for (int k = 0; k < HID; k++) p[k] = gsum[t * HID + k] / c;
    float lg[NCLS];
    float m = -1e30f;
#pragma unroll
    for (int c2 = 0; c2 < NCLS; c2++) {
        float a = bb[c2];
#pragma unroll
        for (int k = 0; k < HID; k++) a = fmaf(p[k], w[k * NCLS + c2], a);
        a = a > 0.f ? a : 0.f;
        lg[c2] = a;
        m = fmaxf(m, a);
    }
    float s = 0.f;
#pragma unroll
    for (int c2 = 0; c2 < NCLS; c2++) s += expf(lg[c2] - m);
    float ls = logf(s);
#pragma unroll
    for (int c2 = 0; c2 < NCLS; c2++) out[t * NCLS + c2] = lg[c2] - m - ls;
}

extern "C" void kernel_launch(void* const* d_in, const int* in_sizes, int n_in,
                              void* d_out, int out_size, void* d_ws, size_t ws_size,
                              hipStream_t stream) {
    const float* x  = (const float*)d_in[0];
    const int* ei   = (const int*)d_in[1];      // [2, E] int32
    const int* batch = (const int*)d_in[2];
    const float* W0 = (const float*)d_in[3];
    const float* b0 = (const float*)d_in[4];
    const float* W1 = (const float*)d_in[5];
    const float* b1 = (const float*)d_in[6];
    const float* W2 = (const float*)d_in[7];
    const float* b2 = (const float*)d_in[8];
    const float* Wl = (const float*)d_in[9];
    const float* bl = (const float*)d_in[10];
    float* out = (float*)d_out;

    const int* esrc = ei;
    const int* edst = ei + NE;

    // bump allocator over workspace
    char* ws = (char*)d_ws;
    size_t off = 0;
    auto alloc = [&](size_t bytes) -> void* {
        void* p = ws + off;
        off = (off + bytes + 511) & ~(size_t)511;
        return p;
    };
    int*   counts  = (int*)alloc(NN * sizeof(int));
    int*   row_ptr = (int*)alloc((NN + 1) * sizeof(int));
    int*   cursor  = (int*)alloc(NN * sizeof(int));
    float* dinv    = (float*)alloc(NN * sizeof(float));
    int*   bsum    = (int*)alloc(256 * sizeof(int));
    int*   csr_src = (int*)alloc(NE * sizeof(int));
    float* tbuf    = (float*)alloc((size_t)NN * HID * sizeof(float));
    float* hA      = (float*)alloc((size_t)NN * HID * sizeof(float));
    float* hB      = (float*)alloc((size_t)NN * HID * sizeof(float));
    float* gsum    = (float*)alloc(NG * HID * sizeof(float));
    float* gcnt    = (float*)alloc(NG * sizeof(float));
    (void)ws_size; (void)in_sizes; (void)n_in; (void)out_size;

    const int egrid = (ET + 255) / 256;

    // ---- CSR build ----
    k_init<<<256, 256, 0, stream>>>(counts, gsum, gcnt);
    k_hist<<<egrid, 256, 0, stream>>>(edst, counts);
    k_scanA<<<NB, SCAN_B, 0, stream>>>(counts, row_ptr, bsum, dinv);
    k_scanB<<<1, 128, 0, stream>>>(bsum);
    k_scanC<<<NB, SCAN_B, 0, stream>>>(row_ptr, cursor, bsum);
    k_scatter<<<egrid, 256, 0, stream>>>(esrc, edst, cursor, csr_src);

    const int gemm_grid = (NN * HID + 255) / 256;   // 32 threads/node
    const int agg_grid = (NN * 32 + 255) / 256;     // 32 lanes/node

    // ---- layer 0 ----
    k_gemm0<<<gemm_grid, 256, 0, stream>>>(x, W0, dinv, tbuf);
    k_agg<<<agg_grid, 256, 0, stream>>>(tbuf, row_ptr, csr_src, dinv, b0, hA);
    // ---- layer 1 ----
    k_gemmh<<<gemm_grid, 256, 0, stream>>>(hA, W1, dinv, tbuf);
    k_agg<<<agg_grid, 256, 0, stream>>>(tbuf, row_ptr, csr_src, dinv, b1, hB);
    // ---- layer 2 ----
    k_gemmh<<<gemm_grid, 256, 0, stream>>>(hB, W2, dinv, tbuf);
    k_agg<<<agg_grid, 256, 0, stream>>>(tbuf, row_ptr, csr_src, dinv, b2, hA);

    // ---- pooling + classifier ----
    k_pool2<<<POOL_GRID, 256, 0, stream>>>(hA, batch, gsum, gcnt);
    k_classify<<<1, 128, 0, stream>>>(gsum, gcnt, Wl, bl, out);
}

// Round 4
// 383.504 us; speedup vs baseline: 1.1796x; 1.1796x over previous
//
#include <hip/hip_runtime.h>
#include <hip/hip_bf16.h>

#define NN 100000
#define NE 1600000
#define NG 128
#define FIN 128
#define HID 32
#define NCLS 10

#define NXCD 8
#define XRANGE (NN / NXCD)                   // 12500 dst nodes per XCD range
#define EG4 (NE / 4)                         // 400000 int4 edge groups
#define SLICES 224
#define GPB ((EG4 + SLICES - 1) / SLICES)    // int4 groups per slice
#define XGRID (SLICES * NXCD)                // 1792 blocks

#define SCAN_B 1024
#define NB ((NN + SCAN_B - 1) / SCAN_B)      // 98

#define POOL_CHUNK 512
#define POOL_SEG 16
#define POOL_GSPAN 32
#define POOL_GRID ((NN + POOL_CHUNK - 1) / POOL_CHUNK)

// ---------------- init: zero accumulators ----------------
__global__ void k_init(int* __restrict__ counts, float* __restrict__ gsum,
                       float* __restrict__ gcnt) {
    int i = blockIdx.x * blockDim.x + threadIdx.x;
    int stride = gridDim.x * blockDim.x;
    for (int j = i; j < NN; j += stride) counts[j] = 0;
    for (int j = i; j < NG * HID; j += stride) gsum[j] = 0.f;
    for (int j = i; j < NG; j += stride) gcnt[j] = 0.f;
}

// ------- degree histogram, XCD-range partitioned: block bid handles dst range (bid&7) -------
__global__ void k_histx(const int* __restrict__ dst, int* __restrict__ counts) {
    const int x = blockIdx.x & (NXCD - 1);
    const int slice = blockIdx.x >> 3;
    const int lo = x * XRANGE, hi = lo + XRANGE;
    const int g0 = slice * GPB;
    int g1 = g0 + GPB; if (g1 > EG4) g1 = EG4;
    for (int g = g0 + threadIdx.x; g < g1; g += 256) {
        const int4 d = ((const int4*)dst)[g];
        if (d.x >= lo && d.x < hi) atomicAdd(&counts[d.x], 1);
        if (d.y >= lo && d.y < hi) atomicAdd(&counts[d.y], 1);
        if (d.z >= lo && d.z < hi) atomicAdd(&counts[d.z], 1);
        if (d.w >= lo && d.w < hi) atomicAdd(&counts[d.w], 1);
    }
}

// ---------------- scan phase A: per-block exclusive scan (+ dinv fused) --------
__global__ void k_scanA(const int* __restrict__ counts, int* __restrict__ row_ptr,
                        int* __restrict__ bsum, float* __restrict__ dinv) {
    __shared__ int lds[SCAN_B];
    int i = blockIdx.x * SCAN_B + threadIdx.x;
    int v = (i < NN) ? counts[i] : 0;
    if (i < NN) dinv[i] = rsqrtf((float)v + 1.0f);
    lds[threadIdx.x] = v;
    __syncthreads();
    int val = v;
    for (int off = 1; off < SCAN_B; off <<= 1) {
        int u = 0;
        if ((int)threadIdx.x >= off) u = lds[threadIdx.x - off];
        __syncthreads();
        if ((int)threadIdx.x >= off) { val += u; lds[threadIdx.x] = val; }
        __syncthreads();
    }
    if (i < NN) row_ptr[i] = val - v;            // exclusive within block
    if (threadIdx.x == SCAN_B - 1) bsum[blockIdx.x] = val;  // block total
}

// ---------------- scan phase B: scan block sums (single block) ----------------
__global__ void k_scanB(int* __restrict__ bsum) {
    __shared__ int lds[128];
    int t = threadIdx.x;
    int v = (t < NB) ? bsum[t] : 0;
    lds[t] = v;
    __syncthreads();
    int val = v;
    for (int off = 1; off < 128; off <<= 1) {
        int u = 0;
        if (t >= off) u = lds[t - off];
        __syncthreads();
        if (t >= off) { val += u; lds[t] = val; }
        __syncthreads();
    }
    if (t < NB) bsum[t] = val - v;               // exclusive
}

// ---------------- scan phase C: add offsets, init cursor ----------------
__global__ void k_scanC(int* __restrict__ row_ptr, int* __restrict__ cursor,
                        const int* __restrict__ bsum) {
    int i = blockIdx.x * SCAN_B + threadIdx.x;
    if (i < NN) {
        int r = row_ptr[i] + bsum[blockIdx.x];
        row_ptr[i] = r;
        cursor[i] = r;
    }
    if (i == 0) row_ptr[NN] = NE;
}

// ------- scatter into CSR, XCD-range partitioned (local atomics + local writes) -------
__global__ void k_scatx(const int* __restrict__ src, const int* __restrict__ dst,
                        int* __restrict__ cursor, int* __restrict__ csr_src) {
    const int x = blockIdx.x & (NXCD - 1);
    const int slice = blockIdx.x >> 3;
    const int lo = x * XRANGE, hi = lo + XRANGE;
    const int g0 = slice * GPB;
    int g1 = g0 + GPB; if (g1 > EG4) g1 = EG4;
    for (int g = g0 + threadIdx.x; g < g1; g += 256) {
        const int4 d = ((const int4*)dst)[g];
        const int4 s = ((const int4*)src)[g];
        if (d.x >= lo && d.x < hi) { int p = atomicAdd(&cursor[d.x], 1); csr_src[p] = s.x; }
        if (d.y >= lo && d.y < hi) { int p = atomicAdd(&cursor[d.y], 1); csr_src[p] = s.y; }
        if (d.z >= lo && d.z < hi) { int p = atomicAdd(&cursor[d.z], 1); csr_src[p] = s.z; }
        if (d.w >= lo && d.w < hi) { int p = atomicAdd(&cursor[d.w], 1); csr_src[p] = s.w; }
    }
}

// ---------------- layer-0 GEMM: t = (x @ W0) * dinv ----------------
__global__ void k_gemm0(const float* __restrict__ x, const float* __restrict__ W,
                        const float* __restrict__ dinv, float* __restrict__ t) {
    __shared__ float Ws[FIN * HID];
    for (int j = threadIdx.x; j < FIN * HID; j += 256) Ws[j] = W[j];
    __syncthreads();
    int gid = blockIdx.x * 256 + threadIdx.x;
    int i = gid >> 5, f = gid & 31;
    if (i >= NN) return;
    const float4* xr = (const float4*)(x + (size_t)i * FIN);
    float acc = 0.f;
#pragma unroll
    for (int k4 = 0; k4 < FIN / 4; k4++) {
        float4 xv = xr[k4];
        int kb = k4 * 4;
        acc = fmaf(xv.x, Ws[(kb + 0) * HID + f], acc);
        acc = fmaf(xv.y, Ws[(kb + 1) * HID + f], acc);
        acc = fmaf(xv.z, Ws[(kb + 2) * HID + f], acc);
        acc = fmaf(xv.w, Ws[(kb + 3) * HID + f], acc);
    }
    t[(size_t)i * HID + f] = acc * dinv[i];
}

// ---------------- hidden GEMM: t = (h @ W) * dinv ----------------
__global__ void k_gemmh(const float* __restrict__ h, const float* __restrict__ W,
                        const float* __restrict__ dinv, float* __restrict__ t) {
    __shared__ float Ws[HID * HID];
    for (int j = threadIdx.x; j < HID * HID; j += 256) Ws[j] = W[j];
    __syncthreads();
    int gid = blockIdx.x * 256 + threadIdx.x;
    int i = gid >> 5, f = gid & 31;
    if (i >= NN) return;
    const float4* hr = (const float4*)(h + (size_t)i * HID);
    float acc = 0.f;
#pragma unroll
    for (int k4 = 0; k4 < HID / 4; k4++) {
        float4 hv = hr[k4];
        int kb = k4 * 4;
        acc = fmaf(hv.x, Ws[(kb + 0) * HID + f], acc);
        acc = fmaf(hv.y, Ws[(kb + 1) * HID + f], acc);
        acc = fmaf(hv.z, Ws[(kb + 2) * HID + f], acc);
        acc = fmaf(hv.w, Ws[(kb + 3) * HID + f], acc);
    }
    t[(size_t)i * HID + f] = acc * dinv[i];
}

// ---------------- aggregation: lane = feature, 32 lanes/node, 8 gathers in flight -----
__global__ void k_agg(const float* __restrict__ t, const int* __restrict__ row_ptr,
                      const int* __restrict__ csr_src, const float* __restrict__ dinv,
                      const float* __restrict__ b, float* __restrict__ hout) {
    int gid = blockIdx.x * blockDim.x + threadIdx.x;
    int i = gid >> 5;                 // node
    int lane = threadIdx.x & 31;      // feature
    if (i >= NN) return;
    float acc = t[(size_t)i * HID + lane];          // self term t'[i]
    const int beg = row_ptr[i], end = row_ptr[i + 1];
    int e = beg;
    for (; e + 8 <= end; e += 8) {
        int s0 = csr_src[e + 0];
        int s1 = csr_src[e + 1];
        int s2 = csr_src[e + 2];
        int s3 = csr_src[e + 3];
        int s4 = csr_src[e + 4];
        int s5 = csr_src[e + 5];
        int s6 = csr_src[e + 6];
        int s7 = csr_src[e + 7];
        float v0 = t[(size_t)s0 * HID + lane];
        float v1 = t[(size_t)s1 * HID + lane];
        float v2 = t[(size_t)s2 * HID + lane];
        float v3 = t[(size_t)s3 * HID + lane];
        float v4 = t[(size_t)s4 * HID + lane];
        float v5 = t[(size_t)s5 * HID + lane];
        float v6 = t[(size_t)s6 * HID + lane];
        float v7 = t[(size_t)s7 * HID + lane];
        acc += ((v0 + v1) + (v2 + v3)) + ((v4 + v5) + (v6 + v7));
    }
    for (; e + 4 <= end; e += 4) {
        int s0 = csr_src[e + 0];
        int s1 = csr_src[e + 1];
        int s2 = csr_src[e + 2];
        int s3 = csr_src[e + 3];
        float v0 = t[(size_t)s0 * HID + lane];
        float v1 = t[(size_t)s1 * HID + lane];
        float v2 = t[(size_t)s2 * HID + lane];
        float v3 = t[(size_t)s3 * HID + lane];
        acc += (v0 + v1) + (v2 + v3);
    }
    for (; e < end; e++) {
        acc += t[(size_t)csr_src[e] * HID + lane];
    }
    float r = fmaf(acc, dinv[i], b[lane]);
    hout[(size_t)i * HID + lane] = fmaxf(r, 0.f);
}

// ---------------- pooling v2: register-segment accumulate -> LDS bins ----------
__global__ void k_pool2(const float* __restrict__ h, const int* __restrict__ batch,
                        float* __restrict__ gsum, float* __restrict__ gcnt) {
    __shared__ float lacc[POOL_GSPAN][HID];
    __shared__ float lcnt[POOL_GSPAN];
    __shared__ int s_gmin;
    const int chunk_start = blockIdx.x * POOL_CHUNK;

    for (int j = threadIdx.x; j < POOL_GSPAN * HID; j += 256) ((float*)lacc)[j] = 0.f;
    if (threadIdx.x < POOL_GSPAN) lcnt[threadIdx.x] = 0.f;
    if (threadIdx.x == 0) {
        int cs = chunk_start < NN ? chunk_start : NN - 1;
        s_gmin = batch[cs];
    }
    __syncthreads();
    const int gmin = s_gmin;

    const int seg = threadIdx.x >> 3;            // 0..31
    const int l = (threadIdx.x & 7) * 4;         // feature quad
    const int i0 = chunk_start + seg * POOL_SEG;

    float4 acc = {0.f, 0.f, 0.f, 0.f};
    float cnt = 0.f;
    int cur_g = -1;

    for (int k = 0; k < POOL_SEG; k++) {
        int i = i0 + k;
        if (i >= NN) break;
        int g = batch[i];
        if (g != cur_g) {
            if (cur_g >= 0) {
                int bin = cur_g - gmin;
                if (bin >= 0 && bin < POOL_GSPAN) {
                    atomicAdd(&lacc[bin][l + 0], acc.x);
                    atomicAdd(&lacc[bin][l + 1], acc.y);
                    atomicAdd(&lacc[bin][l + 2], acc.z);
                    atomicAdd(&lacc[bin][l + 3], acc.w);
                    if (l == 0) atomicAdd(&lcnt[bin], cnt);
                } else {
                    atomicAdd(&gsum[cur_g * HID + l + 0], acc.x);
                    atomicAdd(&gsum[cur_g * HID + l + 1], acc.y);
                    atomicAdd(&gsum[cur_g * HID + l + 2], acc.z);
                    atomicAdd(&gsum[cur_g * HID + l + 3], acc.w);
                    if (l == 0) atomicAdd(&gcnt[cur_g], cnt);
                }
            }
            cur_g = g;
            acc.x = acc.y = acc.z = acc.w = 0.f;
            cnt = 0.f;
        }
        const float4 v = *(const float4*)&h[(size_t)i * HID + l];
        acc.x += v.x; acc.y += v.y; acc.z += v.z; acc.w += v.w;
        cnt += 1.f;
    }
    if (cur_g >= 0) {
        int bin = cur_g - gmin;
        if (bin >= 0 && bin < POOL_GSPAN) {
            atomicAdd(&lacc[bin][l + 0], acc.x);
            atomicAdd(&lacc[bin][l + 1], acc.y);
            atomicAdd(&lacc[bin][l + 2], acc.z);
            atomicAdd(&lacc[bin][l + 3], acc.w);
            if (l == 0) atomicAdd(&lcnt[bin], cnt);
        } else {
            atomicAdd(&gsum[cur_g * HID + l + 0], acc.x);
            atomicAdd(&gsum[cur_g * HID + l + 1], acc.y);
            atomicAdd(&gsum[cur_g * HID + l + 2], acc.z);
            atomicAdd(&gsum[cur_g * HID + l + 3], acc.w);
            if (l == 0) atomicAdd(&gcnt[cur_g], cnt);
        }
    }
    __syncthreads();

    // drain LDS bins: one atomic per touched (graph, feature)
    for (int j = threadIdx.x; j < POOL_GSPAN * HID; j += 256) {
        int bin = j / HID, f = j % HID;
        int g = gmin + bin;
        float v = lacc[bin][f];
        if (g < NG && v != 0.f) atomicAdd(&gsum[g * HID + f], v);
    }
    if (threadIdx.x < POOL_GSPAN) {
        int g = gmin + threadIdx.x;
        float c = lcnt[threadIdx.x];
        if (g < NG && c != 0.f) atomicAdd(&gcnt[g], c);
    }
}

// ---------------- classifier + log_softmax ----------------
__global__ void k_classify(const float* __restrict__ gsum, const float* __restrict__ gcnt,
                           const float* __restrict__ Wl, const float* __restrict__ bl,
                           float* __restrict__ out) {
    __shared__ float w[HID * NCLS];
    __shared__ float bb[NCLS];
    int t = threadIdx.x;
    for (int j = t; j < HID * NCLS; j += blockDim.x) w[j] = Wl[j];
    if (t < NCLS) bb[t] = bl[t];
    __syncthreads();
    if (t >= NG) return;
    float c = gcnt[t];
    c = c > 1.f ? c : 1.f;
    float p[HID];
#pragma unroll
    for (int k = 0; k < HID; k++) p[k] = gsum[t * HID + k] / c;
    float lg[NCLS];
    float m = -1e30f;
#pragma unroll
    for (int c2 = 0; c2 < NCLS; c2++) {
        float a = bb[c2];
#pragma unroll
        for (int k = 0; k < HID; k++) a = fmaf(p[k], w[k * NCLS + c2], a);
        a = a > 0.f ? a : 0.f;
        lg[c2] = a;
        m = fmaxf(m, a);
    }
    float s = 0.f;
#pragma unroll
    for (int c2 = 0; c2 < NCLS; c2++) s += expf(lg[c2] - m);
    float ls = logf(s);
#pragma unroll
    for (int c2 = 0; c2 < NCLS; c2++) out[t * NCLS + c2] = lg[c2] - m - ls;
}

extern "C" void kernel_launch(void* const* d_in, const int* in_sizes, int n_in,
                              void* d_out, int out_size, void* d_ws, size_t ws_size,
                              hipStream_t stream) {
    const float* x  = (const float*)d_in[0];
    const int* ei   = (const int*)d_in[1];      // [2, E] int32
    const int* batch = (const int*)d_in[2];
    const float* W0 = (const float*)d_in[3];
    const float* b0 = (const float*)d_in[4];
    const float* W1 = (const float*)d_in[5];
    const float* b1 = (const float*)d_in[6];
    const float* W2 = (const float*)d_in[7];
    const float* b2 = (const float*)d_in[8];
    const float* Wl = (const float*)d_in[9];
    const float* bl = (const float*)d_in[10];
    float* out = (float*)d_out;

    const int* esrc = ei;
    const int* edst = ei + NE;

    // bump allocator over workspace
    char* ws = (char*)d_ws;
    size_t off = 0;
    auto alloc = [&](size_t bytes) -> void* {
        void* p = ws + off;
        off = (off + bytes + 511) & ~(size_t)511;
        return p;
    };
    int*   counts  = (int*)alloc(NN * sizeof(int));
    int*   row_ptr = (int*)alloc((NN + 1) * sizeof(int));
    int*   cursor  = (int*)alloc(NN * sizeof(int));
    float* dinv    = (float*)alloc(NN * sizeof(float));
    int*   bsum    = (int*)alloc(256 * sizeof(int));
    int*   csr_src = (int*)alloc(NE * sizeof(int));
    float* tbuf    = (float*)alloc((size_t)NN * HID * sizeof(float));
    float* hA      = (float*)alloc((size_t)NN * HID * sizeof(float));
    float* hB      = (float*)alloc((size_t)NN * HID * sizeof(float));
    float* gsum    = (float*)alloc(NG * HID * sizeof(float));
    float* gcnt    = (float*)alloc(NG * sizeof(float));
    (void)ws_size; (void)in_sizes; (void)n_in; (void)out_size;

    // ---- CSR build (XCD-range-partitioned hist + scatter) ----
    k_init<<<256, 256, 0, stream>>>(counts, gsum, gcnt);
    k_histx<<<XGRID, 256, 0, stream>>>(edst, counts);
    k_scanA<<<NB, SCAN_B, 0, stream>>>(counts, row_ptr, bsum, dinv);
    k_scanB<<<1, 128, 0, stream>>>(bsum);
    k_scanC<<<NB, SCAN_B, 0, stream>>>(row_ptr, cursor, bsum);
    k_scatx<<<XGRID, 256, 0, stream>>>(esrc, edst, cursor, csr_src);

    const int gemm_grid = (NN * HID + 255) / 256;   // 32 threads/node
    const int agg_grid = (NN * 32 + 255) / 256;     // 32 lanes/node

    // ---- layer 0 ----
    k_gemm0<<<gemm_grid, 256, 0, stream>>>(x, W0, dinv, tbuf);
    k_agg<<<agg_grid, 256, 0, stream>>>(tbuf, row_ptr, csr_src, dinv, b0, hA);
    // ---- layer 1 ----
    k_gemmh<<<gemm_grid, 256, 0, stream>>>(hA, W1, dinv, tbuf);
    k_agg<<<agg_grid, 256, 0, stream>>>(tbuf, row_ptr, csr_src, dinv, b1, hB);
    // ---- layer 2 ----
    k_gemmh<<<gemm_grid, 256, 0, stream>>>(hB, W2, dinv, tbuf);
    k_agg<<<agg_grid, 256, 0, stream>>>(tbuf, row_ptr, csr_src, dinv, b2, hA);

    // ---- pooling + classifier ----
    k_pool2<<<POOL_GRID, 256, 0, stream>>>(hA, batch, gsum, gcnt);
    k_classify<<<1, 128, 0, stream>>>(gsum, gcnt, Wl, bl, out);
}

// Round 5
// 346.823 us; speedup vs baseline: 1.3044x; 1.1058x over previous
//
#include <hip/hip_runtime.h>
#include <hip/hip_bf16.h>

#define NN 100000
#define NE 1600000
#define NG 128
#define FIN 128
#define HID 32
#define NCLS 10

#define NXCD 8
#define XRANGE (NN / NXCD)                   // 12500 dst nodes per XCD range
#define EG4 (NE / 4)                         // 400000 int4 edge groups
#define SLICES 224
#define GPB ((EG4 + SLICES - 1) / SLICES)    // int4 groups per slice
#define XGRID (SLICES * NXCD)                // 1792 blocks

#define SCAN_B 1024
#define NB ((NN + SCAN_B - 1) / SCAN_B)      // 98

#define POOL_CHUNK 512
#define POOL_SEG 16
#define POOL_GSPAN 32
#define POOL_GRID ((NN + POOL_CHUNK - 1) / POOL_CHUNK)

// GEMM0 MFMA tiling
#define G0_NODES 64                          // nodes per block
#define G0_GRID ((NN + G0_NODES - 1) / G0_NODES)
#define XPAD 136                             // 128 + 8 bf16 pad (272B row stride)

typedef int int4v __attribute__((ext_vector_type(4)));
typedef __attribute__((ext_vector_type(8))) short short8;
typedef __attribute__((ext_vector_type(4))) float f32x4;

__device__ inline unsigned short f2bf(float f) {
    unsigned int u = __float_as_uint(f);
    unsigned int r = u + 0x7FFFu + ((u >> 16) & 1u);   // round-to-nearest-even
    return (unsigned short)(r >> 16);
}

// ---------------- init: zero accumulators ----------------
__global__ void k_init(int* __restrict__ counts, float* __restrict__ gsum,
                       float* __restrict__ gcnt) {
    int i = blockIdx.x * blockDim.x + threadIdx.x;
    int stride = gridDim.x * blockDim.x;
    for (int j = i; j < NN; j += stride) counts[j] = 0;
    for (int j = i; j < NG * HID; j += stride) gsum[j] = 0.f;
    for (int j = i; j < NG; j += stride) gcnt[j] = 0.f;
}

// ------- degree histogram, XCD-range partitioned, nontemporal edge stream -------
__global__ void k_histx(const int* __restrict__ dst, int* __restrict__ counts) {
    const int x = blockIdx.x & (NXCD - 1);
    const int slice = blockIdx.x >> 3;
    const int lo = x * XRANGE, hi = lo + XRANGE;
    const int g0 = slice * GPB;
    int g1 = g0 + GPB; if (g1 > EG4) g1 = EG4;
    for (int g = g0 + threadIdx.x; g < g1; g += 256) {
        const int4v d = __builtin_nontemporal_load((const int4v*)dst + g);
        if (d.x >= lo && d.x < hi) atomicAdd(&counts[d.x], 1);
        if (d.y >= lo && d.y < hi) atomicAdd(&counts[d.y], 1);
        if (d.z >= lo && d.z < hi) atomicAdd(&counts[d.z], 1);
        if (d.w >= lo && d.w < hi) atomicAdd(&counts[d.w], 1);
    }
}

// ---------------- scan phase A: per-block exclusive scan (+ dinv fused) --------
__global__ void k_scanA(const int* __restrict__ counts, int* __restrict__ row_ptr,
                        int* __restrict__ bsum, float* __restrict__ dinv) {
    __shared__ int lds[SCAN_B];
    int i = blockIdx.x * SCAN_B + threadIdx.x;
    int v = (i < NN) ? counts[i] : 0;
    if (i < NN) dinv[i] = rsqrtf((float)v + 1.0f);
    lds[threadIdx.x] = v;
    __syncthreads();
    int val = v;
    for (int off = 1; off < SCAN_B; off <<= 1) {
        int u = 0;
        if ((int)threadIdx.x >= off) u = lds[threadIdx.x - off];
        __syncthreads();
        if ((int)threadIdx.x >= off) { val += u; lds[threadIdx.x] = val; }
        __syncthreads();
    }
    if (i < NN) row_ptr[i] = val - v;            // exclusive within block
    if (threadIdx.x == SCAN_B - 1) bsum[blockIdx.x] = val;  // block total
}

// ---------------- scan phase B: scan block sums (single block) ----------------
__global__ void k_scanB(int* __restrict__ bsum) {
    __shared__ int lds[128];
    int t = threadIdx.x;
    int v = (t < NB) ? bsum[t] : 0;
    lds[t] = v;
    __syncthreads();
    int val = v;
    for (int off = 1; off < 128; off <<= 1) {
        int u = 0;
        if (t >= off) u = lds[t - off];
        __syncthreads();
        if (t >= off) { val += u; lds[t] = val; }
        __syncthreads();
    }
    if (t < NB) bsum[t] = val - v;               // exclusive
}

// ---------------- scan phase C: add offsets, init cursor ----------------
__global__ void k_scanC(int* __restrict__ row_ptr, int* __restrict__ cursor,
                        const int* __restrict__ bsum) {
    int i = blockIdx.x * SCAN_B + threadIdx.x;
    if (i < NN) {
        int r = row_ptr[i] + bsum[blockIdx.x];
        row_ptr[i] = r;
        cursor[i] = r;
    }
    if (i == 0) row_ptr[NN] = NE;
}

// ------- scatter into CSR, XCD-range partitioned, nontemporal edge stream -------
__global__ void k_scatx(const int* __restrict__ src, const int* __restrict__ dst,
                        int* __restrict__ cursor, int* __restrict__ csr_src) {
    const int x = blockIdx.x & (NXCD - 1);
    const int slice = blockIdx.x >> 3;
    const int lo = x * XRANGE, hi = lo + XRANGE;
    const int g0 = slice * GPB;
    int g1 = g0 + GPB; if (g1 > EG4) g1 = EG4;
    for (int g = g0 + threadIdx.x; g < g1; g += 256) {
        const int4v d = __builtin_nontemporal_load((const int4v*)dst + g);
        const int4v s = __builtin_nontemporal_load((const int4v*)src + g);
        if (d.x >= lo && d.x < hi) { int p = atomicAdd(&cursor[d.x], 1); csr_src[p] = s.x; }
        if (d.y >= lo && d.y < hi) { int p = atomicAdd(&cursor[d.y], 1); csr_src[p] = s.y; }
        if (d.z >= lo && d.z < hi) { int p = atomicAdd(&cursor[d.z], 1); csr_src[p] = s.z; }
        if (d.w >= lo && d.w < hi) { int p = atomicAdd(&cursor[d.w], 1); csr_src[p] = s.w; }
    }
}

// ---------------- layer-0 GEMM via bf16 MFMA: t = (x @ W0) * dinv ----------------
// block = 256 threads = 4 waves; 64 nodes/block; N=32 (2 tiles), K=128 (4 steps)
__global__ void k_gemm0(const float* __restrict__ x, const float* __restrict__ W,
                        const float* __restrict__ dinv, float* __restrict__ t) {
    __shared__ __align__(16) unsigned short x_lds[G0_NODES][XPAD];
    __shared__ __align__(16) unsigned short wt_lds[HID][XPAD];   // transposed W: [n][k]
    const int tid = threadIdx.x;
    const int node0 = blockIdx.x * G0_NODES;

    // stage x tile (coalesced float4 reads, bf16 RNE convert)
#pragma unroll
    for (int r = 0; r < 8; r++) {
        int q = tid + 256 * r;                 // 2048 float4 per block
        int row = q >> 5;                      // 32 float4 per row
        int c4 = q & 31;
        float4 xv = {0.f, 0.f, 0.f, 0.f};
        int node = node0 + row;
        if (node < NN) xv = ((const float4*)(x + (size_t)node * FIN))[c4];
        ushort4 b;
        b.x = f2bf(xv.x); b.y = f2bf(xv.y); b.z = f2bf(xv.z); b.w = f2bf(xv.w);
        *(ushort4*)&x_lds[row][c4 * 4] = b;
    }
    // stage W transposed: wt_lds[n][k]
#pragma unroll
    for (int r = 0; r < 16; r++) {
        int q = tid + 256 * r;                 // 4096 elements
        int k = q >> 5, n = q & 31;
        wt_lds[n][k] = f2bf(W[q]);
    }
    __syncthreads();

    const int w = tid >> 6;                    // wave id, 16 nodes each
    const int lane = tid & 63;
    const int row = lane & 15;
    const int kg = lane >> 4;                  // k-group 0..3
    const int w16 = w * 16;

    f32x4 acc0 = {0.f, 0.f, 0.f, 0.f};
    f32x4 acc1 = {0.f, 0.f, 0.f, 0.f};
#pragma unroll
    for (int s = 0; s < 4; s++) {              // K steps of 32
        short8 a  = *(const short8*)&x_lds[w16 + row][s * 32 + kg * 8];
        short8 b0 = *(const short8*)&wt_lds[row][s * 32 + kg * 8];        // N-tile 0
        short8 b1 = *(const short8*)&wt_lds[16 + row][s * 32 + kg * 8];   // N-tile 1
        acc0 = __builtin_amdgcn_mfma_f32_16x16x32_bf16(a, b0, acc0, 0, 0, 0);
        acc1 = __builtin_amdgcn_mfma_f32_16x16x32_bf16(a, b1, acc1, 0, 0, 0);
    }

    // D layout: col = lane&15 (feature), row = kg*4 + j (node within 16)
    const int f = lane & 15;
#pragma unroll
    for (int j = 0; j < 4; j++) {
        int node = node0 + w16 + kg * 4 + j;
        if (node < NN) {
            float di = dinv[node];
            t[(size_t)node * HID + f]      = acc0[j] * di;
            t[(size_t)node * HID + 16 + f] = acc1[j] * di;
        }
    }
}

// ---------------- hidden GEMM: t = (h @ W) * dinv ----------------
__global__ void k_gemmh(const float* __restrict__ h, const float* __restrict__ W,
                        const float* __restrict__ dinv, float* __restrict__ t) {
    __shared__ float Ws[HID * HID];
    for (int j = threadIdx.x; j < HID * HID; j += 256) Ws[j] = W[j];
    __syncthreads();
    int gid = blockIdx.x * 256 + threadIdx.x;
    int i = gid >> 5, f = gid & 31;
    if (i >= NN) return;
    const float4* hr = (const float4*)(h + (size_t)i * HID);
    float acc = 0.f;
#pragma unroll
    for (int k4 = 0; k4 < HID / 4; k4++) {
        float4 hv = hr[k4];
        int kb = k4 * 4;
        acc = fmaf(hv.x, Ws[(kb + 0) * HID + f], acc);
        acc = fmaf(hv.y, Ws[(kb + 1) * HID + f], acc);
        acc = fmaf(hv.z, Ws[(kb + 2) * HID + f], acc);
        acc = fmaf(hv.w, Ws[(kb + 3) * HID + f], acc);
    }
    t[(size_t)i * HID + f] = acc * dinv[i];
}

// ---------------- aggregation: lane = feature, 32 lanes/node, 8 gathers in flight -----
__global__ void k_agg(const float* __restrict__ t, const int* __restrict__ row_ptr,
                      const int* __restrict__ csr_src, const float* __restrict__ dinv,
                      const float* __restrict__ b, float* __restrict__ hout) {
    int gid = blockIdx.x * blockDim.x + threadIdx.x;
    int i = gid >> 5;                 // node
    int lane = threadIdx.x & 31;      // feature
    if (i >= NN) return;
    float acc = t[(size_t)i * HID + lane];          // self term t'[i]
    const int beg = row_ptr[i], end = row_ptr[i + 1];
    int e = beg;
    for (; e + 8 <= end; e += 8) {
        int s0 = csr_src[e + 0];
        int s1 = csr_src[e + 1];
        int s2 = csr_src[e + 2];
        int s3 = csr_src[e + 3];
        int s4 = csr_src[e + 4];
        int s5 = csr_src[e + 5];
        int s6 = csr_src[e + 6];
        int s7 = csr_src[e + 7];
        float v0 = t[(size_t)s0 * HID + lane];
        float v1 = t[(size_t)s1 * HID + lane];
        float v2 = t[(size_t)s2 * HID + lane];
        float v3 = t[(size_t)s3 * HID + lane];
        float v4 = t[(size_t)s4 * HID + lane];
        float v5 = t[(size_t)s5 * HID + lane];
        float v6 = t[(size_t)s6 * HID + lane];
        float v7 = t[(size_t)s7 * HID + lane];
        acc += ((v0 + v1) + (v2 + v3)) + ((v4 + v5) + (v6 + v7));
    }
    for (; e + 4 <= end; e += 4) {
        int s0 = csr_src[e + 0];
        int s1 = csr_src[e + 1];
        int s2 = csr_src[e + 2];
        int s3 = csr_src[e + 3];
        float v0 = t[(size_t)s0 * HID + lane];
        float v1 = t[(size_t)s1 * HID + lane];
        float v2 = t[(size_t)s2 * HID + lane];
        float v3 = t[(size_t)s3 * HID + lane];
        acc += (v0 + v1) + (v2 + v3);
    }
    for (; e < end; e++) {
        acc += t[(size_t)csr_src[e] * HID + lane];
    }
    float r = fmaf(acc, dinv[i], b[lane]);
    hout[(size_t)i * HID + lane] = fmaxf(r, 0.f);
}

// ---------------- pooling v2: register-segment accumulate -> LDS bins ----------
__global__ void k_pool2(const float* __restrict__ h, const int* __restrict__ batch,
                        float* __restrict__ gsum, float* __restrict__ gcnt) {
    __shared__ float lacc[POOL_GSPAN][HID];
    __shared__ float lcnt[POOL_GSPAN];
    __shared__ int s_gmin;
    const int chunk_start = blockIdx.x * POOL_CHUNK;

    for (int j = threadIdx.x; j < POOL_GSPAN * HID; j += 256) ((float*)lacc)[j] = 0.f;
    if (threadIdx.x < POOL_GSPAN) lcnt[threadIdx.x] = 0.f;
    if (threadIdx.x == 0) {
        int cs = chunk_start < NN ? chunk_start : NN - 1;
        s_gmin = batch[cs];
    }
    __syncthreads();
    const int gmin = s_gmin;

    const int seg = threadIdx.x >> 3;            // 0..31
    const int l = (threadIdx.x & 7) * 4;         // feature quad
    const int i0 = chunk_start + seg * POOL_SEG;

    float4 acc = {0.f, 0.f, 0.f, 0.f};
    float cnt = 0.f;
    int cur_g = -1;

    for (int k = 0; k < POOL_SEG; k++) {
        int i = i0 + k;
        if (i >= NN) break;
        int g = batch[i];
        if (g != cur_g) {
            if (cur_g >= 0) {
                int bin = cur_g - gmin;
                if (bin >= 0 && bin < POOL_GSPAN) {
                    atomicAdd(&lacc[bin][l + 0], acc.x);
                    atomicAdd(&lacc[bin][l + 1], acc.y);
                    atomicAdd(&lacc[bin][l + 2], acc.z);
                    atomicAdd(&lacc[bin][l + 3], acc.w);
                    if (l == 0) atomicAdd(&lcnt[bin], cnt);
                } else {
                    atomicAdd(&gsum[cur_g * HID + l + 0], acc.x);
                    atomicAdd(&gsum[cur_g * HID + l + 1], acc.y);
                    atomicAdd(&gsum[cur_g * HID + l + 2], acc.z);
                    atomicAdd(&gsum[cur_g * HID + l + 3], acc.w);
                    if (l == 0) atomicAdd(&gcnt[cur_g], cnt);
                }
            }
            cur_g = g;
            acc.x = acc.y = acc.z = acc.w = 0.f;
            cnt = 0.f;
        }
        const float4 v = *(const float4*)&h[(size_t)i * HID + l];
        acc.x += v.x; acc.y += v.y; acc.z += v.z; acc.w += v.w;
        cnt += 1.f;
    }
    if (cur_g >= 0) {
        int bin = cur_g - gmin;
        if (bin >= 0 && bin < POOL_GSPAN) {
            atomicAdd(&lacc[bin][l + 0], acc.x);
            atomicAdd(&lacc[bin][l + 1], acc.y);
            atomicAdd(&lacc[bin][l + 2], acc.z);
            atomicAdd(&lacc[bin][l + 3], acc.w);
            if (l == 0) atomicAdd(&lcnt[bin], cnt);
        } else {
            atomicAdd(&gsum[cur_g * HID + l + 0], acc.x);
            atomicAdd(&gsum[cur_g * HID + l + 1], acc.y);
            atomicAdd(&gsum[cur_g * HID + l + 2], acc.z);
            atomicAdd(&gsum[cur_g * HID + l + 3], acc.w);
            if (l == 0) atomicAdd(&gcnt[cur_g], cnt);
        }
    }
    __syncthreads();

    // drain LDS bins: one atomic per touched (graph, feature)
    for (int j = threadIdx.x; j < POOL_GSPAN * HID; j += 256) {
        int bin = j / HID, f = j % HID;
        int g = gmin + bin;
        float v = lacc[bin][f];
        if (g < NG && v != 0.f) atomicAdd(&gsum[g * HID + f], v);
    }
    if (threadIdx.x < POOL_GSPAN) {
        int g = gmin + threadIdx.x;
        float c = lcnt[threadIdx.x];
        if (g < NG && c != 0.f) atomicAdd(&gcnt[g], c);
    }
}

// ---------------- classifier + log_softmax ----------------
__global__ void k_classify(const float* __restrict__ gsum, const float* __restrict__ gcnt,
                           const float* __restrict__ Wl, const float* __restrict__ bl,
                           float* __restrict__ out) {
    __shared__ float w[HID * NCLS];
    __shared__ float bb[NCLS];
    int t = threadIdx.x;
    for (int j = t; j < HID * NCLS; j += blockDim.x) w[j] = Wl[j];
    if (t < NCLS) bb[t] = bl[t];
    __syncthreads();
    if (t >= NG) return;
    float c = gcnt[t];
    c = c > 1.f ? c : 1.f;
    float p[HID];
#pragma unroll
    for (int k = 0; k < HID; k++) p[k] = gsum[t * HID + k] / c;
    float lg[NCLS];
    float m = -1e30f;
#pragma unroll
    for (int c2 = 0; c2 < NCLS; c2++) {
        float a = bb[c2];
#pragma unroll
        for (int k = 0; k < HID; k++) a = fmaf(p[k], w[k * NCLS + c2], a);
        a = a > 0.f ? a : 0.f;
        lg[c2] = a;
        m = fmaxf(m, a);
    }
    float s = 0.f;
#pragma unroll
    for (int c2 = 0; c2 < NCLS; c2++) s += expf(lg[c2] - m);
    float ls = logf(s);
#pragma unroll
    for (int c2 = 0; c2 < NCLS; c2++) out[t * NCLS + c2] = lg[c2] - m - ls;
}

extern "C" void kernel_launch(void* const* d_in, const int* in_sizes, int n_in,
                              void* d_out, int out_size, void* d_ws, size_t ws_size,
                              hipStream_t stream) {
    const float* x  = (const float*)d_in[0];
    const int* ei   = (const int*)d_in[1];      // [2, E] int32
    const int* batch = (const int*)d_in[2];
    const float* W0 = (const float*)d_in[3];
    const float* b0 = (const float*)d_in[4];
    const float* W1 = (const float*)d_in[5];
    const float* b1 = (const float*)d_in[6];
    const float* W2 = (const float*)d_in[7];
    const float* b2 = (const float*)d_in[8];
    const float* Wl = (const float*)d_in[9];
    const float* bl = (const float*)d_in[10];
    float* out = (float*)d_out;

    const int* esrc = ei;
    const int* edst = ei + NE;

    // bump allocator over workspace
    char* ws = (char*)d_ws;
    size_t off = 0;
    auto alloc = [&](size_t bytes) -> void* {
        void* p = ws + off;
        off = (off + bytes + 511) & ~(size_t)511;
        return p;
    };
    int*   counts  = (int*)alloc(NN * sizeof(int));
    int*   row_ptr = (int*)alloc((NN + 1) * sizeof(int));
    int*   cursor  = (int*)alloc(NN * sizeof(int));
    float* dinv    = (float*)alloc(NN * sizeof(float));
    int*   bsum    = (int*)alloc(256 * sizeof(int));
    int*   csr_src = (int*)alloc(NE * sizeof(int));
    float* tbuf    = (float*)alloc((size_t)NN * HID * sizeof(float));
    float* hA      = (float*)alloc((size_t)NN * HID * sizeof(float));
    float* hB      = (float*)alloc((size_t)NN * HID * sizeof(float));
    float* gsum    = (float*)alloc(NG * HID * sizeof(float));
    float* gcnt    = (float*)alloc(NG * sizeof(float));
    (void)ws_size; (void)in_sizes; (void)n_in; (void)out_size;

    // ---- CSR build (XCD-range-partitioned hist + scatter) ----
    k_init<<<256, 256, 0, stream>>>(counts, gsum, gcnt);
    k_histx<<<XGRID, 256, 0, stream>>>(edst, counts);
    k_scanA<<<NB, SCAN_B, 0, stream>>>(counts, row_ptr, bsum, dinv);
    k_scanB<<<1, 128, 0, stream>>>(bsum);
    k_scanC<<<NB, SCAN_B, 0, stream>>>(row_ptr, cursor, bsum);
    k_scatx<<<XGRID, 256, 0, stream>>>(esrc, edst, cursor, csr_src);

    const int gemm_grid = (NN * HID + 255) / 256;   // 32 threads/node
    const int agg_grid = (NN * 32 + 255) / 256;     // 32 lanes/node

    // ---- layer 0 (MFMA) ----
    k_gemm0<<<G0_GRID, 256, 0, stream>>>(x, W0, dinv, tbuf);
    k_agg<<<agg_grid, 256, 0, stream>>>(tbuf, row_ptr, csr_src, dinv, b0, hA);
    // ---- layer 1 ----
    k_gemmh<<<gemm_grid, 256, 0, stream>>>(hA, W1, dinv, tbuf);
    k_agg<<<agg_grid, 256, 0, stream>>>(tbuf, row_ptr, csr_src, dinv, b1, hB);
    // ---- layer 2 ----
    k_gemmh<<<gemm_grid, 256, 0, stream>>>(hB, W2, dinv, tbuf);
    k_agg<<<agg_grid, 256, 0, stream>>>(tbuf, row_ptr, csr_src, dinv, b2, hA);

    // ---- pooling + classifier ----
    k_pool2<<<POOL_GRID, 256, 0, stream>>>(hA, batch, gsum, gcnt);
    k_classify<<<1, 128, 0, stream>>>(gsum, gcnt, Wl, bl, out);
}